// Round 1
// baseline (339.249 us; speedup 1.0000x reference)
//
#include <hip/hip_runtime.h>
#include <stdint.h>

typedef unsigned short u16;
typedef __bf16 bf16x8_t __attribute__((ext_vector_type(8)));
typedef float f32x4 __attribute__((ext_vector_type(4)));

#define T_LEN 2048
#define NHEADS 16
#define DHEAD 64
#define DMODEL 1024

__device__ __forceinline__ u16 f2bf(float f) {
  union { float f; uint32_t u; } v; v.f = f;
  uint32_t r = v.u + 0x7FFFu + ((v.u >> 16) & 1u);
  return (u16)(r >> 16);
}

// ---------------- fp32 -> bf16 conversion ----------------
__global__ void cvt_bf16_k(const float* __restrict__ s, u16* __restrict__ d, int n) {
  int i = (blockIdx.x * blockDim.x + threadIdx.x) * 4;
  if (i >= n) return;
  float4 f = *(const float4*)(s + i);
  u16 o[4] = { f2bf(f.x), f2bf(f.y), f2bf(f.z), f2bf(f.w) };
  *(uint2*)(d + i) = *(const uint2*)o;
}

// ---------------- GEMM: C = A(bf16[M,K]) * Bw(bf16[N,K])^T + bias ----------------
// MODE 0: write fp32 [M,N] (final projection into d_out)
// MODE 1: write bf16 scatter into [B,H,T,Dh]   (Q, K)
// MODE 2: write bf16 scatter into [B,H,Dh,T]   (V transposed)
template <int MODE>
__global__ __launch_bounds__(256, 2) void gemm_bt_k(
    const u16* __restrict__ A, const u16* __restrict__ Bw,
    const float* __restrict__ bias, void* __restrict__ out,
    int M, int N, int K)
{
  __shared__ __align__(16) u16 As[128][40];  // +8 pad: 2-way LDS aliasing only (free)
  __shared__ __align__(16) u16 Bs[128][40];
  const int m0 = blockIdx.x * 128;
  const int n0 = blockIdx.y * 128;
  const int tid = threadIdx.x;
  const int lane = tid & 63;
  const int w = tid >> 6;
  const int wm = (w >> 1) * 64, wn = (w & 1) * 64;
  const int col = lane & 15, quad = lane >> 4;

  f32x4 acc[4][4] = {};

  for (int k0 = 0; k0 < K; k0 += 32) {
    __syncthreads();
    // stage A-tile 128x32 and B-tile 128x32 (bf16), 16B chunks
    for (int c = tid; c < 512; c += 256) {
      int r = c >> 2, kc = (c & 3) * 8;
      *(bf16x8_t*)&As[r][kc] = *(const bf16x8_t*)&A[(size_t)(m0 + r) * K + k0 + kc];
      *(bf16x8_t*)&Bs[r][kc] = *(const bf16x8_t*)&Bw[(size_t)(n0 + r) * K + k0 + kc];
    }
    __syncthreads();
    bf16x8_t af[4], bfr[4];
#pragma unroll
    for (int i = 0; i < 4; i++) af[i]  = *(const bf16x8_t*)&As[wm + i * 16 + col][quad * 8];
#pragma unroll
    for (int j = 0; j < 4; j++) bfr[j] = *(const bf16x8_t*)&Bs[wn + j * 16 + col][quad * 8];
#pragma unroll
    for (int i = 0; i < 4; i++)
#pragma unroll
      for (int j = 0; j < 4; j++)
        acc[i][j] = __builtin_amdgcn_mfma_f32_16x16x32_bf16(af[i], bfr[j], acc[i][j], 0, 0, 0);
  }

#pragma unroll
  for (int i = 0; i < 4; i++) {
#pragma unroll
    for (int j = 0; j < 4; j++) {
      int ncol = n0 + wn + j * 16 + col;
      float bv = bias[ncol];
#pragma unroll
      for (int r = 0; r < 4; r++) {
        int m = m0 + wm + i * 16 + quad * 4 + r;  // C/D layout: row = quad*4+reg, col = lane&15
        float v = acc[i][j][r] + bv;
        if (MODE == 0) {
          ((float*)out)[(size_t)m * N + ncol] = v;
        } else {
          int b = m >> 11, t = m & 2047, h = ncol >> 6, d = ncol & 63;
          size_t idx;
          if (MODE == 1) idx = (((size_t)(b * NHEADS + h)) * T_LEN + t) * DHEAD + d;
          else           idx = (((size_t)(b * NHEADS + h)) * DHEAD + d) * T_LEN + t;
          ((u16*)out)[idx] = f2bf(v);
        }
      }
    }
  }
}

// ---------------- Flash-style causal attention ----------------
// Q,K: bf16 [B*H, T, 64]; Vt: bf16 [B*H, 64, T]; Y: bf16 [B, T, 1024]
// block = 256 thr = 4 waves; block handles 64 q-rows of one (b,h); wave w -> 16 q-rows.
__global__ __launch_bounds__(256, 2) void attn_k(
    const u16* __restrict__ Q, const u16* __restrict__ Kb,
    const u16* __restrict__ Vt, u16* __restrict__ Y)
{
  __shared__ __align__(16) u16 Ks[64][72];        // [key][d], +8 pad
  __shared__ __align__(16) u16 Vs[64][72];        // [d][key], +8 pad
  __shared__ __align__(16) u16 Ps[4][16][72];     // per-wave P: [q][key]
  const int blk = blockIdx.x;
  const int qt = blk & 31;          // q-tile index (T/64 = 32)
  const int bh = blk >> 5;          // b*16+h
  const int q0 = qt * 64;
  const int tid = threadIdx.x, lane = tid & 63, w = tid >> 6;
  const int col = lane & 15, quad = lane >> 4;
  const int qw = q0 + w * 16;

  // Q fragments (A-layout: m=lane&15, k=quad*8+j), loaded once from global
  bf16x8_t qf[2];
  {
    const u16* p = Q + ((size_t)bh * T_LEN + qw + col) * DHEAD + quad * 8;
    qf[0] = *(const bf16x8_t*)p;
    qf[1] = *(const bf16x8_t*)(p + 32);
  }

  float m_i[4], l_i[4];
#pragma unroll
  for (int r = 0; r < 4; r++) { m_i[r] = -1e30f; l_i[r] = 0.f; }
  f32x4 o[4] = {};

  for (int kt = 0; kt <= qt; ++kt) {   // causal: skip key-tiles entirely above diagonal
    const int k0 = kt * 64;
    __syncthreads();
    for (int c = tid; c < 512; c += 256) {
      int r = c >> 3, kc = (c & 7) * 8;
      *(bf16x8_t*)&Ks[r][kc] = *(const bf16x8_t*)&Kb[((size_t)bh * T_LEN + k0 + r) * DHEAD + kc];
      *(bf16x8_t*)&Vs[r][kc] = *(const bf16x8_t*)&Vt[((size_t)bh * DHEAD + r) * T_LEN + k0 + kc];
    }
    __syncthreads();

    // S = Q K^T for 4 key sub-tiles of 16 (K=64 via 2 chained mfma)
    f32x4 s[4];
#pragma unroll
    for (int nt = 0; nt < 4; nt++) {
      bf16x8_t kf0 = *(const bf16x8_t*)&Ks[nt * 16 + col][quad * 8];
      bf16x8_t kf1 = *(const bf16x8_t*)&Ks[nt * 16 + col][32 + quad * 8];
      f32x4 a = {};
      a = __builtin_amdgcn_mfma_f32_16x16x32_bf16(qf[0], kf0, a, 0, 0, 0);
      a = __builtin_amdgcn_mfma_f32_16x16x32_bf16(qf[1], kf1, a, 0, 0, 0);
      s[nt] = a;
    }

    const bool diag = (kt == qt);
#pragma unroll
    for (int r = 0; r < 4; r++) {
      const int qrow = qw + quad * 4 + r;
      float mx = -1e30f;
#pragma unroll
      for (int nt = 0; nt < 4; nt++) {
        float v = s[nt][r] * 0.125f;              // 1/sqrt(64)
        if (diag && (k0 + nt * 16 + col) > qrow) v = -1e30f;  // causal mask
        s[nt][r] = v;
        mx = fmaxf(mx, v);
      }
#pragma unroll
      for (int off = 1; off < 16; off <<= 1)      // row-max over 16 cols (same quad group)
        mx = fmaxf(mx, __shfl_xor(mx, off));
      float mnew = fmaxf(m_i[r], mx);
      float alpha = __expf(m_i[r] - mnew);
      float sum = 0.f;
#pragma unroll
      for (int nt = 0; nt < 4; nt++) {
        float p = __expf(s[nt][r] - mnew);
        s[nt][r] = p;
        sum += p;
      }
#pragma unroll
      for (int off = 1; off < 16; off <<= 1)
        sum += __shfl_xor(sum, off);
      l_i[r] = l_i[r] * alpha + sum;
      m_i[r] = mnew;
#pragma unroll
      for (int dt = 0; dt < 4; dt++) o[dt][r] *= alpha;
      // C-layout -> LDS (per-wave buffer), becomes A-layout on read
#pragma unroll
      for (int nt = 0; nt < 4; nt++)
        Ps[w][quad * 4 + r][nt * 16 + col] = f2bf(s[nt][r]);
    }

    // O += P * V  (A from Ps LDS, B = Vt rows: b_frag = Vt[d][k])
#pragma unroll
    for (int ks = 0; ks < 2; ks++) {
      bf16x8_t pf = *(const bf16x8_t*)&Ps[w][col][ks * 32 + quad * 8];
#pragma unroll
      for (int dt = 0; dt < 4; dt++) {
        bf16x8_t vf = *(const bf16x8_t*)&Vs[dt * 16 + col][ks * 32 + quad * 8];
        o[dt] = __builtin_amdgcn_mfma_f32_16x16x32_bf16(pf, vf, o[dt], 0, 0, 0);
      }
    }
  }

  // epilogue: O /= l, write to [B, T, C] bf16
  const int b = bh >> 4, h = bh & 15;
#pragma unroll
  for (int r = 0; r < 4; r++) {
    float inv = 1.0f / l_i[r];
    int t = qw + quad * 4 + r;
#pragma unroll
    for (int dt = 0; dt < 4; dt++) {
      Y[((size_t)(b * T_LEN + t)) * DMODEL + h * DHEAD + dt * 16 + col] =
          f2bf(o[dt][r] * inv);
    }
  }
}

// ---------------- launch ----------------
extern "C" void kernel_launch(void* const* d_in, const int* in_sizes, int n_in,
                              void* d_out, int out_size, void* d_ws, size_t ws_size,
                              hipStream_t stream) {
  const float* x  = (const float*)d_in[0];
  const float* Wk = (const float*)d_in[1];
  const float* bk = (const float*)d_in[2];
  const float* Wq = (const float*)d_in[3];
  const float* bq = (const float*)d_in[4];
  const float* Wv = (const float*)d_in[5];
  const float* bv = (const float*)d_in[6];
  const float* Wp = (const float*)d_in[7];
  const float* bp = (const float*)d_in[8];

  char* ws = (char*)d_ws;
  const size_t MB = 1u << 20;
  u16* xb   = (u16*)(ws);            // 8 MB  : x bf16 [4096,1024]
  u16* wqb  = (u16*)(ws + 8 * MB);   // 2 MB
  u16* wkb  = (u16*)(ws + 10 * MB);  // 2 MB
  u16* wvb  = (u16*)(ws + 12 * MB);  // 2 MB
  u16* wpb  = (u16*)(ws + 14 * MB);  // 2 MB
  u16* qb   = (u16*)(ws + 16 * MB);  // 8 MB : [B,H,T,64]
  u16* kb   = (u16*)(ws + 24 * MB);  // 8 MB : [B,H,T,64]
  u16* vtb  = (u16*)(ws + 32 * MB);  // 8 MB : [B,H,64,T]
  u16* yatt = (u16*)(ws + 40 * MB);  // 8 MB : [B,T,1024]

  cvt_bf16_k<<<4096, 256, 0, stream>>>(x,  xb,  4194304);
  cvt_bf16_k<<<1024, 256, 0, stream>>>(Wq, wqb, 1048576);
  cvt_bf16_k<<<1024, 256, 0, stream>>>(Wk, wkb, 1048576);
  cvt_bf16_k<<<1024, 256, 0, stream>>>(Wv, wvb, 1048576);
  cvt_bf16_k<<<1024, 256, 0, stream>>>(Wp, wpb, 1048576);

  dim3 g(32, 8);
  gemm_bt_k<1><<<g, 256, 0, stream>>>(xb, wqb, bq, qb,  4096, 1024, 1024);
  gemm_bt_k<1><<<g, 256, 0, stream>>>(xb, wkb, bk, kb,  4096, 1024, 1024);
  gemm_bt_k<2><<<g, 256, 0, stream>>>(xb, wvb, bv, vtb, 4096, 1024, 1024);

  attn_k<<<1024, 256, 0, stream>>>(qb, kb, vtb, yatt);

  gemm_bt_k<0><<<g, 256, 0, stream>>>(yatt, wpb, bp, d_out, 4096, 1024, 1024);
}

// Round 2
// 274.981 us; speedup vs baseline: 1.2337x; 1.2337x over previous
//
#include <hip/hip_runtime.h>
#include <stdint.h>

typedef unsigned short u16;
typedef __bf16 bf16x8_t __attribute__((ext_vector_type(8)));
typedef float f32x4 __attribute__((ext_vector_type(4)));

#define T_LEN 2048
#define NHEADS 16
#define DHEAD 64
#define DMODEL 1024
#define QSCALE 0.1803368801111f  /* 0.125 * log2(e): softmax done in exp2 domain */

__device__ __forceinline__ u16 f2bf(float f) {
  union { float f; uint32_t u; } v; v.f = f;
  uint32_t r = v.u + 0x7FFFu + ((v.u >> 16) & 1u);
  return (u16)(r >> 16);
}

// async global->LDS, 16B per lane, dest = wave-uniform base + lane*16
__device__ __forceinline__ void gload16(const u16* g, u16* l) {
  __builtin_amdgcn_global_load_lds((const __attribute__((address_space(1))) void*)g,
                                   (__attribute__((address_space(3))) void*)l, 16, 0, 0);
}

// ---------------- fp32 -> bf16 conversion ----------------
__global__ void cvt_bf16_k(const float* __restrict__ s, u16* __restrict__ d, int n) {
  int i = (blockIdx.x * blockDim.x + threadIdx.x) * 4;
  if (i >= n) return;
  float4 f = *(const float4*)(s + i);
  u16 o[4] = { f2bf(f.x), f2bf(f.y), f2bf(f.z), f2bf(f.w) };
  *(uint2*)(d + i) = *(const uint2*)o;
}

// ---------------- GEMM: C = A(bf16[M,K]) * Bw(bf16[N,K])^T + bias ----------------
// MODE 0: fp32 out [M,N] = o0, bias b0
// MODE 3: fused QKV epilogue; n-section 0 -> Q scatter [B,H,T,Dh] *QSCALE (o0,b0)
//                             section 1 -> K scatter [B,H,T,Dh]          (o1,b1)
//                             section 2 -> V scatter [B,H,Dh,T]          (o2,b2)
template <int TM, int TN, int MODE>
__global__ __launch_bounds__(256, 2) void gemm_k(
    const u16* __restrict__ A, const u16* __restrict__ Bw,
    const float* __restrict__ b0, const float* __restrict__ b1, const float* __restrict__ b2,
    void* __restrict__ o0, void* __restrict__ o1, void* __restrict__ o2,
    int M, int N, int K)
{
  // unpadded: layout must be lane-contiguous for global_load_lds (m104/m108 caveat)
  __shared__ __align__(16) u16 As[TM][32];
  __shared__ __align__(16) u16 Bs[TN][32];
  const int m0 = blockIdx.x * TM, n0 = blockIdx.y * TN;
  const int tid = threadIdx.x, lane = tid & 63, w = tid >> 6;
  const int col = lane & 15, quad = lane >> 4;
  constexpr int WM = TM / 2, WN = TN / 2;
  const int wm = (w >> 1) * WM, wn = (w & 1) * WN;
  constexpr int NI = WM / 16, NJ = WN / 16;
  const int lrow = lane >> 2, lk = (lane & 3) * 8;

  f32x4 acc[NI][NJ] = {};

  for (int k0 = 0; k0 < K; k0 += 32) {
    __syncthreads();
#pragma unroll
    for (int i = 0; i < TM / 64; i++) {
      int r = (i * 4 + w) * 16;
      gload16(&A[(size_t)(m0 + r + lrow) * K + k0 + lk], &As[r][0]);
    }
#pragma unroll
    for (int i = 0; i < TN / 64; i++) {
      int r = (i * 4 + w) * 16;
      gload16(&Bw[(size_t)(n0 + r + lrow) * K + k0 + lk], &Bs[r][0]);
    }
    __syncthreads();  // drains vmcnt -> LDS valid
    bf16x8_t af[NI], bfr[NJ];
#pragma unroll
    for (int i = 0; i < NI; i++) af[i]  = *(const bf16x8_t*)&As[wm + i * 16 + col][quad * 8];
#pragma unroll
    for (int j = 0; j < NJ; j++) bfr[j] = *(const bf16x8_t*)&Bs[wn + j * 16 + col][quad * 8];
#pragma unroll
    for (int i = 0; i < NI; i++)
#pragma unroll
      for (int j = 0; j < NJ; j++)
        acc[i][j] = __builtin_amdgcn_mfma_f32_16x16x32_bf16(af[i], bfr[j], acc[i][j], 0, 0, 0);
  }

#pragma unroll
  for (int i = 0; i < NI; i++) {
#pragma unroll
    for (int j = 0; j < NJ; j++) {
      int ncol = n0 + wn + j * 16 + col;
      if (MODE == 0) {
        float bias = b0[ncol];
#pragma unroll
        for (int r = 0; r < 4; r++) {
          int m = m0 + wm + i * 16 + quad * 4 + r;  // C/D: row=quad*4+r, col=lane&15
          ((float*)o0)[(size_t)m * N + ncol] = acc[i][j][r] + bias;
        }
      } else {
        int sect = ncol >> 10, nc = ncol & 1023;
        const float* bp = sect == 0 ? b0 : (sect == 1 ? b1 : b2);
        u16* op = sect == 0 ? (u16*)o0 : (sect == 1 ? (u16*)o1 : (u16*)o2);
        float bias = bp[nc];
        float scal = sect == 0 ? QSCALE : 1.0f;
        int h = nc >> 6, d = nc & 63;
#pragma unroll
        for (int r = 0; r < 4; r++) {
          int m = m0 + wm + i * 16 + quad * 4 + r;
          int b = m >> 11, t = m & 2047;
          float v = (acc[i][j][r] + bias) * scal;
          size_t idx = sect < 2 ? ((((size_t)(b * NHEADS + h)) * T_LEN + t) * DHEAD + d)
                                : ((((size_t)(b * NHEADS + h)) * DHEAD + d) * T_LEN + t);
          op[idx] = f2bf(v);
        }
      }
    }
  }
}

// ---------------- Flash-style causal attention, barrier-free k-loop ----------------
// Q,K: bf16 [B*H, T, 64] (Q pre-scaled by QSCALE); Vt: bf16 [B*H, 64, T]; Y: bf16 [B,T,1024]
// grid = (16 pair-slots, 32 bh). Block processes q-tiles {pair, 31-pair}: equal work (33 kt).
// 4 waves x 16 q-rows; K/V fragments loaded straight from global (no LDS staging, no barriers).
__global__ __launch_bounds__(256, 2) void attn_k(
    const u16* __restrict__ Q, const u16* __restrict__ Kb,
    const u16* __restrict__ Vt, u16* __restrict__ Y)
{
  __shared__ __align__(16) u16 Ps[4][16][68];  // stride 68: quad stride = 8 banks -> conflict-free
  const int pair = blockIdx.x;   // 0..15
  const int bh = blockIdx.y;     // 0..31
  const int tid = threadIdx.x, lane = tid & 63, w = tid >> 6;
  const int col = lane & 15, quad = lane >> 4;
  const int b = bh >> 4, h = bh & 15;

  for (int pass = 0; pass < 2; ++pass) {
    const int qt = pass ? 31 - pair : pair;
    const int qw = qt * 64 + w * 16;

    bf16x8_t qf0, qf1;
    {
      const u16* p = Q + ((size_t)bh * T_LEN + qw + col) * DHEAD + quad * 8;
      qf0 = *(const bf16x8_t*)p;
      qf1 = *(const bf16x8_t*)(p + 32);
    }

    float m_i[4], l_i[4];
#pragma unroll
    for (int r = 0; r < 4; r++) { m_i[r] = -1e30f; l_i[r] = 0.f; }
    f32x4 o[4] = {};

    for (int kt = 0; kt <= qt; ++kt) {
      const int k0 = kt * 64;
      // K fragments direct from global (B-frag: lane(col,quad) <- K[k0+nt*16+col][quad*8..])
      const u16* kp = Kb + ((size_t)bh * T_LEN + k0 + col) * DHEAD + quad * 8;
      bf16x8_t kfa[4], kfb[4];
#pragma unroll
      for (int nt = 0; nt < 4; nt++) {
        kfa[nt] = *(const bf16x8_t*)(kp + nt * 16 * DHEAD);
        kfb[nt] = *(const bf16x8_t*)(kp + nt * 16 * DHEAD + 32);
      }
      f32x4 s[4];
#pragma unroll
      for (int nt = 0; nt < 4; nt++) {
        f32x4 a = {};
        a = __builtin_amdgcn_mfma_f32_16x16x32_bf16(qf0, kfa[nt], a, 0, 0, 0);
        a = __builtin_amdgcn_mfma_f32_16x16x32_bf16(qf1, kfb[nt], a, 0, 0, 0);
        s[nt] = a;
      }
      // V fragments issued before softmax so their latency hides under VALU
      bf16x8_t vf[4][2];
#pragma unroll
      for (int dt = 0; dt < 4; dt++)
#pragma unroll
        for (int ks = 0; ks < 2; ks++)
          vf[dt][ks] = *(const bf16x8_t*)&Vt[((size_t)bh * DHEAD + dt * 16 + col) * T_LEN +
                                             k0 + ks * 32 + quad * 8];

      const bool diag = (kt == qt);
#pragma unroll
      for (int r = 0; r < 4; r++) {
        const int qrow = qw + quad * 4 + r;
        float mx = -1e30f;
        if (diag) {
#pragma unroll
          for (int nt = 0; nt < 4; nt++) {
            float v = s[nt][r];
            if ((k0 + nt * 16 + col) > qrow) v = -1e30f;
            s[nt][r] = v;
            mx = fmaxf(mx, v);
          }
        } else {
#pragma unroll
          for (int nt = 0; nt < 4; nt++) mx = fmaxf(mx, s[nt][r]);
        }
#pragma unroll
        for (int off = 1; off < 16; off <<= 1)
          mx = fmaxf(mx, __shfl_xor(mx, off));
        float mnew = fmaxf(m_i[r], mx);
        float alpha = exp2f(m_i[r] - mnew);
        float sum = 0.f;
#pragma unroll
        for (int nt = 0; nt < 4; nt++) {
          float p = exp2f(s[nt][r] - mnew);
          s[nt][r] = p;
          sum += p;
        }
#pragma unroll
        for (int off = 1; off < 16; off <<= 1)
          sum += __shfl_xor(sum, off);
        l_i[r] = l_i[r] * alpha + sum;
        m_i[r] = mnew;
#pragma unroll
        for (int dt = 0; dt < 4; dt++) o[dt][r] *= alpha;
#pragma unroll
        for (int nt = 0; nt < 4; nt++)
          Ps[w][quad * 4 + r][nt * 16 + col] = f2bf(s[nt][r]);
      }
      // O += P*V ; Ps write->read is same-wave LDS (in-order, no barrier needed)
#pragma unroll
      for (int ks = 0; ks < 2; ks++) {
        bf16x8_t pf = *(const bf16x8_t*)&Ps[w][col][ks * 32 + quad * 8];
#pragma unroll
        for (int dt = 0; dt < 4; dt++)
          o[dt] = __builtin_amdgcn_mfma_f32_16x16x32_bf16(pf, vf[dt][ks], o[dt], 0, 0, 0);
      }
    }

    // epilogue: O /= l, write [B,T,C] bf16
#pragma unroll
    for (int r = 0; r < 4; r++) {
      float inv = 1.0f / l_i[r];
      int t = qw + quad * 4 + r;
#pragma unroll
      for (int dt = 0; dt < 4; dt++) {
        Y[((size_t)(b * T_LEN + t)) * DMODEL + h * DHEAD + dt * 16 + col] =
            f2bf(o[dt][r] * inv);
      }
    }
  }
}

// ---------------- launch ----------------
extern "C" void kernel_launch(void* const* d_in, const int* in_sizes, int n_in,
                              void* d_out, int out_size, void* d_ws, size_t ws_size,
                              hipStream_t stream) {
  const float* x  = (const float*)d_in[0];
  const float* Wk = (const float*)d_in[1];
  const float* bk = (const float*)d_in[2];
  const float* Wq = (const float*)d_in[3];
  const float* bq = (const float*)d_in[4];
  const float* Wv = (const float*)d_in[5];
  const float* bv = (const float*)d_in[6];
  const float* Wp = (const float*)d_in[7];
  const float* bp = (const float*)d_in[8];

  char* ws = (char*)d_ws;
  const size_t MB = 1u << 20;
  u16* xb    = (u16*)(ws);            // 8 MB : x bf16 [4096,1024]
  u16* wqkv  = (u16*)(ws + 8 * MB);   // 6 MB : [Wq;Wk;Wv] bf16 [3072,1024]
  u16* wpb   = (u16*)(ws + 14 * MB);  // 2 MB
  u16* qb    = (u16*)(ws + 16 * MB);  // 8 MB : [B,H,T,64] (pre-scaled)
  u16* kb    = (u16*)(ws + 24 * MB);  // 8 MB : [B,H,T,64]
  u16* vtb   = (u16*)(ws + 32 * MB);  // 8 MB : [B,H,64,T]
  u16* yatt  = (u16*)(ws + 40 * MB);  // 8 MB : [B,T,1024]

  cvt_bf16_k<<<4096, 256, 0, stream>>>(x,  xb, 4194304);
  cvt_bf16_k<<<1024, 256, 0, stream>>>(Wq, wqkv,           1048576);
  cvt_bf16_k<<<1024, 256, 0, stream>>>(Wk, wqkv + 1048576, 1048576);
  cvt_bf16_k<<<1024, 256, 0, stream>>>(Wv, wqkv + 2097152, 1048576);
  cvt_bf16_k<<<1024, 256, 0, stream>>>(Wp, wpb, 1048576);

  // fused QKV projection: [4096,1024] x [3072,1024]^T
  dim3 gqkv(32, 24);
  gemm_k<128, 128, 3><<<gqkv, 256, 0, stream>>>(xb, wqkv, bq, bk, bv,
                                                qb, kb, vtb, 4096, 3072, 1024);

  dim3 ga(16, 32);
  attn_k<<<ga, 256, 0, stream>>>(qb, kb, vtb, yatt);

  // final projection -> fp32 out
  dim3 gp(32, 16);
  gemm_k<128, 64, 0><<<gp, 256, 0, stream>>>(yatt, wpb, bp, nullptr, nullptr,
                                             d_out, nullptr, nullptr, 4096, 1024, 1024);
}